// Round 1
// baseline (146.582 us; speedup 1.0000x reference)
//
#include <hip/hip_runtime.h>
#include <hip/hip_bf16.h>

#define NB 16
#define NC 4
#define NL 4096
#define NK 256
#define NS 128
#define NW (NL - NS + 1)           /* 3969 */
#define WPB 128                    /* windows per block */
#define NWT ((NW + WPB - 1) / WPB) /* 32 window tiles */
#define KPB 128                    /* k per block (K split by blockIdx.y) */
#define EPSF 1e-8f

typedef __attribute__((ext_vector_type(8))) short bf16x8;
typedef __attribute__((ext_vector_type(4))) float floatx4;

__device__ inline short f2bf(float f) {
    __hip_bfloat16 h = __float2bfloat16(f);
    short s;
    __builtin_memcpy(&s, &h, sizeof(short));
    return s;
}

// Single kernel: no workspace, shapelet norm fused into B staging,
// window norm applied in fp32 per-channel epilogue (raw-bf16 MFMA inputs).
__global__ __launch_bounds__(256, 2)
void mcs_kernel(const float* __restrict__ x,
                const float* __restrict__ shp,
                float* __restrict__ out) {
    __shared__ bf16x8 bs[2][KPB * 16];            // 2 x 32 KB, swizzled, dbuf
    __shared__ alignas(16) short xcp[NC][4][264]; // 8.25 KB shifted raw-bf16 x
    __shared__ alignas(16) float scratch[NC][264];// x^2 -> prefix -> epilogue red
    __shared__ float invw[NC][WPB];               // 2 KB window inv-norms

    const int wt = blockIdx.x, kh2 = blockIdx.y, b = blockIdx.z;
    const int w0 = wt * WPB;
    const int tid = threadIdx.x;
    const int lane = tid & 63, wv = tid >> 6;

    // ---- issue B(c=0) global prefetch (fp32, coalesced float4) ----
    float4 f4[16];
    {
        const float4* bb = (const float4*)(shp + (size_t)(kh2 * KPB) * NS);
        #pragma unroll
        for (int i = 0; i < 16; i++) f4[i] = bb[i * 256 + tid];
    }

    // ---- stage x: thread tid holds element o=tid of each channel ----
    float xv[NC];
    #pragma unroll
    for (int c = 0; c < NC; c++) {
        int g = w0 + tid;
        xv[c] = (g < NL) ? x[((size_t)b * NC + c) * NL + g] : 0.f;
    }
    #pragma unroll
    for (int c = 0; c < NC; c++) {
        short hv = f2bf(xv[c]);                  // RAW bf16, no scaling
        #pragma unroll
        for (int r = 0; r < 4; r++) {
            int o2 = tid - r;
            if (o2 >= 0) xcp[c][r][o2] = hv;
        }
        scratch[c][tid] = xv[c] * xv[c];
    }
    __syncthreads();

    // ---- in-place inclusive prefix scan: wave wv scans channel wv ----
    {
        float4 v = *(const float4*)&scratch[wv][lane * 4];
        v.y += v.x; v.z += v.y; v.w += v.z;
        float tt = v.w;
        #pragma unroll
        for (int o = 1; o < 64; o <<= 1) {
            float u = __shfl_up(tt, o, 64);
            if (lane >= o) tt += u;
        }
        float excl = tt - v.w;
        v.x += excl; v.y += excl; v.z += excl; v.w += excl;
        *(float4*)&scratch[wv][lane * 4] = v;
    }
    __syncthreads();

    // ---- window inverse norms from prefix sums (2 per thread) ----
    #pragma unroll
    for (int i = 0; i < 2; i++) {
        int idx = tid + 256 * i;
        int c = idx >> 7, o = idx & 127;
        float nn = scratch[c][o + 127] - (o ? scratch[c][o - 1] : 0.f);
        int w = w0 + o;
        invw[c][o] = (w < NW) ? 1.f / fmaxf(sqrtf(fmaxf(nn, 0.f)), EPSF) : 0.f;
    }

    // ---- B staging: row-norm (shfl over 32-lane group) + cvt + swizzled store
    auto stage_b = [&](int buf) {
        #pragma unroll
        for (int i = 0; i < 16; i++) {
            float4 v = f4[i];
            float ss = v.x * v.x + v.y * v.y + v.z * v.z + v.w * v.w;
            #pragma unroll
            for (int o = 1; o < 32; o <<= 1) ss += __shfl_xor(ss, o, 32);
            float inv = 1.f / fmaxf(sqrtf(ss), EPSF);
            int e = i * 1024 + tid * 4;          // element within 128x128 chunk
            int k = e >> 7, u = (e >> 3) & 15, h = (e >> 2) & 1;
            uint2 pw;
            pw.x = (unsigned)(unsigned short)f2bf(v.x * inv)
                 | ((unsigned)(unsigned short)f2bf(v.y * inv) << 16);
            pw.y = (unsigned)(unsigned short)f2bf(v.z * inv)
                 | ((unsigned)(unsigned short)f2bf(v.w * inv) << 16);
            *(uint2*)((short*)&bs[buf][(k << 4) | (u ^ (k & 15))] + h * 4) = pw;
        }
    };
    stage_b(0);
    __syncthreads();

    // ---- main loop ----
    const int m = lane & 15, q = lane >> 4, r = m & 3;
    const int kh = wv & 1, wh = wv >> 1;

    floatx4 tot[4][4];
    #pragma unroll
    for (int mt = 0; mt < 4; mt++)
        #pragma unroll
        for (int kt = 0; kt < 4; kt++) tot[mt][kt] = (floatx4){0.f, 0.f, 0.f, 0.f};

    int cur = 0;
    #pragma unroll
    for (int c = 0; c < NC; c++) {
        if (c < NC - 1) {   // prefetch next channel's B (in flight over MFMA)
            const float4* bb =
                (const float4*)(shp + ((size_t)(c + 1) * NK + kh2 * KPB) * NS);
            #pragma unroll
            for (int i = 0; i < 16; i++) f4[i] = bb[i * 256 + tid];
        }
        floatx4 part[4][4];
        #pragma unroll
        for (int s0 = 0; s0 < NS; s0 += 32) {
            bf16x8 a[4];
            #pragma unroll
            for (int mt = 0; mt < 4; mt++) {     // raw bit-copy: zero VALU
                int ts = wh * 64 + mt * 16 + m + s0 + q * 8;
                const uint2* pp = (const uint2*)&xcp[c][r][ts - r];
                union { uint2 uu[2]; bf16x8 v; } cv;
                cv.uu[0] = pp[0]; cv.uu[1] = pp[1];
                a[mt] = cv.v;
            }
            int cc = (s0 >> 3) + q;
            #pragma unroll
            for (int kt = 0; kt < 4; kt++) {
                int k = kh * 64 + kt * 16 + m;
                bf16x8 bf = bs[cur][(k << 4) | (cc ^ (k & 15))];
                #pragma unroll
                for (int mt = 0; mt < 4; mt++) {
                    part[mt][kt] = (s0 == 0)
                        ? __builtin_amdgcn_mfma_f32_16x16x32_bf16(
                              a[mt], bf, (floatx4){0.f, 0.f, 0.f, 0.f}, 0, 0, 0)
                        : __builtin_amdgcn_mfma_f32_16x16x32_bf16(
                              a[mt], bf, part[mt][kt], 0, 0, 0);
                }
            }
        }
        // fp32 per-channel scale-accumulate: tot += invw[row] * part
        #pragma unroll
        for (int mt = 0; mt < 4; mt++) {
            const float4 iv = *(const float4*)&invw[c][wh * 64 + mt * 16 + q * 4];
            floatx4 ivv = (floatx4){iv.x, iv.y, iv.z, iv.w};
            #pragma unroll
            for (int kt = 0; kt < 4; kt++) tot[mt][kt] += ivv * part[mt][kt];
        }
        if (c < NC - 1) {
            stage_b(cur ^ 1);       // dbuf: no WAR on buffer being read
            __syncthreads();        // writes visible before next channel reads
            cur ^= 1;
        }
    }

    // ---- epilogue: max over wave's 64 windows per k, then atomicMax ----
    #pragma unroll
    for (int kt = 0; kt < 4; kt++) {
        floatx4 v0 = tot[0][kt], v1 = tot[1][kt], v2 = tot[2][kt], v3 = tot[3][kt];
        float mx = fmaxf(fmaxf(fmaxf(v0.x, v0.y), fmaxf(v0.z, v0.w)),
                         fmaxf(fmaxf(v1.x, v1.y), fmaxf(v1.z, v1.w)));
        mx = fmaxf(mx, fmaxf(fmaxf(fmaxf(v2.x, v2.y), fmaxf(v2.z, v2.w)),
                             fmaxf(fmaxf(v3.x, v3.y), fmaxf(v3.z, v3.w))));
        mx = fmaxf(mx, __shfl_xor(mx, 16, 64));
        mx = fmaxf(mx, __shfl_xor(mx, 32, 64));
        if (lane < 16) scratch[wv][kt * 16 + lane] = mx;   // own row, no race
    }
    __syncthreads();
    if (tid < 128) {
        int khh = tid >> 6, j = tid & 63;
        // waves {wh0,wh1} with same kh: rows {khh, khh+2}
        float v = fmaxf(scratch[khh][j], scratch[khh + 2][j]);
        v = fmaxf(v, 0.f) * 0.25f;    // ReLU + 1/C, nonneg -> int-monotonic
        int kg = kh2 * KPB + khh * 64 + j;
        atomicMax((int*)out + (size_t)b * NK + kg, __float_as_int(v));
    }
}

extern "C" void kernel_launch(void* const* d_in, const int* in_sizes, int n_in,
                              void* d_out, int out_size, void* d_ws, size_t ws_size,
                              hipStream_t stream) {
    (void)in_sizes; (void)n_in; (void)out_size; (void)d_ws; (void)ws_size;
    const float* x   = (const float*)d_in[0];
    const float* shp = (const float*)d_in[1];
    float* out = (float*)d_out;

    mcs_kernel<<<dim3(NWT, 2, NB), 256, 0, stream>>>(x, shp, out);
}

// Round 2
// 97.132 us; speedup vs baseline: 1.5091x; 1.5091x over previous
//
#include <hip/hip_runtime.h>
#include <hip/hip_bf16.h>

#define NB 16
#define NC 4
#define NL 4096
#define NK 256
#define NS 128
#define NW (NL - NS + 1)           /* 3969 */
#define WPB 128                    /* windows per block */
#define NWT ((NW + WPB - 1) / WPB) /* 32 window tiles */
#define KPB 128                    /* k per block (K split by blockIdx.y) */
#define EPSF 1e-8f

typedef __attribute__((ext_vector_type(8))) short bf16x8;
typedef __attribute__((ext_vector_type(4))) float floatx4;

typedef __attribute__((address_space(3))) unsigned int* lds_ptr_t;
typedef const __attribute__((address_space(1))) unsigned int* gbl_ptr_t;

__device__ inline short f2bf(float f) {
    __hip_bfloat16 h = __float2bfloat16(f);
    short s;
    __builtin_memcpy(&s, &h, sizeof(short));
    return s;
}

__device__ inline void gload_lds16(const void* g, void* l) {
    __builtin_amdgcn_global_load_lds((gbl_ptr_t)g, (lds_ptr_t)l, 16, 0, 0);
}

// K1: normalize shapelets (fp32 in), write bf16 bits PRE-SWIZZLED within each
// 256B row so the main kernel can global_load_lds linearly. One wave per (c,k).
__global__ __launch_bounds__(64)
void norm_shp_kernel(const float* __restrict__ shp, short* __restrict__ shpn) {
    int ck = blockIdx.x;
    int k = ck & (NK - 1);
    int lane = threadIdx.x;
    const float* p = shp + (size_t)ck * NS;
    float v0 = p[lane];
    float v1 = p[lane + 64];
    float ss = v0 * v0 + v1 * v1;
    #pragma unroll
    for (int o = 32; o > 0; o >>= 1) ss += __shfl_xor(ss, o, 64);
    float rn = 1.f / fmaxf(sqrtf(ss), EPSF);
    // swizzled element positions: 16B unit u of row k goes to unit u^(k&15)
    int s0 = lane, s1 = lane + 64;
    int d0 = ((((s0 >> 3) ^ (k & 15)) << 3) | (s0 & 7));
    int d1 = ((((s1 >> 3) ^ (k & 15)) << 3) | (s1 & 7));
    shpn[(size_t)ck * NS + d0] = f2bf(v0 * rn);
    shpn[(size_t)ck * NS + d1] = f2bf(v1 * rn);
}

// K2: main kernel. Block = (wtile, khalf, b). Wave wv: windows (wv>>1)*64..+63,
// k quarter (wv&1)*64..+63 of this block's 128-k half. Raw-bf16 A from shifted
// LDS copies, B via global_load_lds (pre-swizzled source), fp32 window-norm in
// per-channel epilogue, dual accumulators, atomicMax output.
__global__ __launch_bounds__(256, 2)
void mcs_main_kernel(const float* __restrict__ x,
                     const short* __restrict__ shpn,
                     float* __restrict__ out) {
    __shared__ bf16x8 bs[2][KPB * 16];            // 2 x 32 KB swizzled B, dbuf
    __shared__ alignas(16) short xcp[NC][4][264]; // 8.25 KB shifted raw-bf16 x
    __shared__ alignas(16) float scratch[NC][264];// x^2 -> prefix -> epilogue red
    __shared__ float invw[NC][WPB];               // 2 KB window inv-norms

    const int wt = blockIdx.x, kh2 = blockIdx.y, b = blockIdx.z;
    const int w0 = wt * WPB;
    const int tid = threadIdx.x;
    const int lane = tid & 63, wv = tid >> 6;

    // ---- B staging: zero-VGPR zero-VALU direct-to-LDS, 8 x 1KB per wave ----
    auto stage = [&](int buf, int c) {
        const char* gsrc = (const char*)shpn +
                           ((size_t)(c * NK + kh2 * KPB) * NS) * 2;
        char* lbase = (char*)&bs[buf][0];
        #pragma unroll
        for (int i = 0; i < 8; i++) {
            int off = (wv * 8 + i) * 1024;
            gload_lds16(gsrc + off + lane * 16, lbase + off);
        }
    };
    stage(0, 0);   // c=0 loads in flight over the whole prologue

    // ---- stage x: thread tid holds element o=tid of each channel ----
    float xv[NC];
    #pragma unroll
    for (int c = 0; c < NC; c++) {
        int g = w0 + tid;
        xv[c] = (g < NL) ? x[((size_t)b * NC + c) * NL + g] : 0.f;
    }
    #pragma unroll
    for (int c = 0; c < NC; c++) {
        short hv = f2bf(xv[c]);                  // RAW bf16, no scaling
        #pragma unroll
        for (int r = 0; r < 4; r++) {
            int o2 = tid - r;
            if (o2 >= 0) xcp[c][r][o2] = hv;
        }
        scratch[c][tid] = xv[c] * xv[c];
    }
    __syncthreads();

    // ---- in-place inclusive prefix scan: wave wv scans channel wv ----
    {
        float4 v = *(const float4*)&scratch[wv][lane * 4];
        v.y += v.x; v.z += v.y; v.w += v.z;
        float tt = v.w;
        #pragma unroll
        for (int o = 1; o < 64; o <<= 1) {
            float u = __shfl_up(tt, o, 64);
            if (lane >= o) tt += u;
        }
        float excl = tt - v.w;
        v.x += excl; v.y += excl; v.z += excl; v.w += excl;
        *(float4*)&scratch[wv][lane * 4] = v;
    }
    __syncthreads();

    // ---- window inverse norms from prefix sums (2 per thread) ----
    #pragma unroll
    for (int i = 0; i < 2; i++) {
        int idx = tid + 256 * i;
        int c = idx >> 7, o = idx & 127;
        float nn = scratch[c][o + 127] - (o ? scratch[c][o - 1] : 0.f);
        int w = w0 + o;
        invw[c][o] = (w < NW) ? 1.f / fmaxf(sqrtf(fmaxf(nn, 0.f)), EPSF) : 0.f;
    }
    __syncthreads();   // invw visible; c=0 B staged (barrier drains vmcnt)

    // ---- main loop ----
    const int m = lane & 15, q = lane >> 4, r = m & 3;
    const int kh = wv & 1, wh = wv >> 1;

    floatx4 tot[4][4];
    #pragma unroll
    for (int mt = 0; mt < 4; mt++)
        #pragma unroll
        for (int kt = 0; kt < 4; kt++) tot[mt][kt] = (floatx4){0.f, 0.f, 0.f, 0.f};

    int cur = 0;
    #pragma unroll
    for (int c = 0; c < NC; c++) {
        if (c < NC - 1) stage(cur ^ 1, c + 1);   // in flight over MFMA phase
        floatx4 part[4][4];
        #pragma unroll
        for (int s0 = 0; s0 < NS; s0 += 32) {
            bf16x8 a[4];
            #pragma unroll
            for (int mt = 0; mt < 4; mt++) {     // raw bit-copy: zero VALU
                int ts = wh * 64 + mt * 16 + m + s0 + q * 8;
                const uint2* pp = (const uint2*)&xcp[c][r][ts - r];
                union { uint2 uu[2]; bf16x8 v; } cv;
                cv.uu[0] = pp[0]; cv.uu[1] = pp[1];
                a[mt] = cv.v;
            }
            int cc = (s0 >> 3) + q;
            #pragma unroll
            for (int kt = 0; kt < 4; kt++) {
                int k = kh * 64 + kt * 16 + m;   // k&15 == m
                bf16x8 bf = bs[cur][(k << 4) | (cc ^ m)];
                #pragma unroll
                for (int mt = 0; mt < 4; mt++) {
                    part[mt][kt] = (s0 == 0)
                        ? __builtin_amdgcn_mfma_f32_16x16x32_bf16(
                              a[mt], bf, (floatx4){0.f, 0.f, 0.f, 0.f}, 0, 0, 0)
                        : __builtin_amdgcn_mfma_f32_16x16x32_bf16(
                              a[mt], bf, part[mt][kt], 0, 0, 0);
                }
            }
        }
        // fp32 per-channel scale-accumulate: tot += invw[row] * part
        #pragma unroll
        for (int mt = 0; mt < 4; mt++) {
            const float4 iv = *(const float4*)&invw[c][wh * 64 + mt * 16 + q * 4];
            floatx4 ivv = (floatx4){iv.x, iv.y, iv.z, iv.w};
            #pragma unroll
            for (int kt = 0; kt < 4; kt++) tot[mt][kt] += ivv * part[mt][kt];
        }
        if (c < NC - 1) {
            asm volatile("s_waitcnt vmcnt(0)" ::: "memory");
            __syncthreads();        // next buf staged, all waves done with cur
            cur ^= 1;
        }
    }

    // ---- epilogue: max over wave's 64 windows per k, then atomicMax ----
    __syncthreads();   // scratch reused as per-wave reduction rows
    #pragma unroll
    for (int kt = 0; kt < 4; kt++) {
        floatx4 v0 = tot[0][kt], v1 = tot[1][kt], v2 = tot[2][kt], v3 = tot[3][kt];
        float mx = fmaxf(fmaxf(fmaxf(v0.x, v0.y), fmaxf(v0.z, v0.w)),
                         fmaxf(fmaxf(v1.x, v1.y), fmaxf(v1.z, v1.w)));
        mx = fmaxf(mx, fmaxf(fmaxf(fmaxf(v2.x, v2.y), fmaxf(v2.z, v2.w)),
                             fmaxf(fmaxf(v3.x, v3.y), fmaxf(v3.z, v3.w))));
        mx = fmaxf(mx, __shfl_xor(mx, 16, 64));
        mx = fmaxf(mx, __shfl_xor(mx, 32, 64));
        if (lane < 16) scratch[wv][kt * 16 + lane] = mx;   // own row, no race
    }
    __syncthreads();
    if (tid < 128) {
        int khh = tid >> 6, j = tid & 63;
        // waves {wh=0,wh=1} with same kh: scratch rows {khh, khh+2}
        float v = fmaxf(scratch[khh][j], scratch[khh + 2][j]);
        v = fmaxf(v, 0.f) * 0.25f;    // ReLU + 1/C, nonneg -> int-monotonic
        int kg = kh2 * KPB + khh * 64 + j;
        atomicMax((int*)out + (size_t)b * NK + kg, __float_as_int(v));
    }
}

extern "C" void kernel_launch(void* const* d_in, const int* in_sizes, int n_in,
                              void* d_out, int out_size, void* d_ws, size_t ws_size,
                              hipStream_t stream) {
    (void)in_sizes; (void)n_in; (void)out_size; (void)ws_size;
    const float* x   = (const float*)d_in[0];
    const float* shp = (const float*)d_in[1];
    float* out = (float*)d_out;

    short* shpn = (short*)d_ws;     // 256 KB of workspace

    norm_shp_kernel<<<NC * NK, 64, 0, stream>>>(shp, shpn);
    mcs_main_kernel<<<dim3(NWT, 2, NB), 256, 0, stream>>>(x, shpn, out);
}

// Round 3
// 80.750 us; speedup vs baseline: 1.8153x; 1.2029x over previous
//
#include <hip/hip_runtime.h>
#include <hip/hip_bf16.h>

#define NB 16
#define NC 4
#define NL 4096
#define NK 256
#define NS 128
#define NW (NL - NS + 1)           /* 3969 */
#define WPB 128                    /* windows per block */
#define NWT ((NW + WPB - 1) / WPB) /* 32 window tiles */
#define KPB 64                     /* k per block (K split 4-way by blockIdx.y) */
#define EPSF 1e-8f

typedef __attribute__((ext_vector_type(8))) short bf16x8;
typedef __attribute__((ext_vector_type(4))) float floatx4;

typedef __attribute__((address_space(3))) unsigned int* lds_ptr_t;
typedef const __attribute__((address_space(1))) unsigned int* gbl_ptr_t;

__device__ inline short f2bf(float f) {
    __hip_bfloat16 h = __float2bfloat16(f);
    short s;
    __builtin_memcpy(&s, &h, sizeof(short));
    return s;
}

__device__ inline void gload_lds16(const void* g, void* l) {
    __builtin_amdgcn_global_load_lds((gbl_ptr_t)g, (lds_ptr_t)l, 16, 0, 0);
}

// K1: normalize shapelets (fp32 in), write bf16 bits PRE-SWIZZLED within each
// 256B row so the main kernel can global_load_lds linearly. One wave per (c,k).
__global__ __launch_bounds__(64)
void norm_shp_kernel(const float* __restrict__ shp, short* __restrict__ shpn) {
    int ck = blockIdx.x;
    int k = ck & (NK - 1);
    int lane = threadIdx.x;
    const float* p = shp + (size_t)ck * NS;
    float v0 = p[lane];
    float v1 = p[lane + 64];
    float ss = v0 * v0 + v1 * v1;
    #pragma unroll
    for (int o = 32; o > 0; o >>= 1) ss += __shfl_xor(ss, o, 64);
    float rn = 1.f / fmaxf(sqrtf(ss), EPSF);
    // swizzled element positions: 16B unit u of row k goes to unit u^(k&15)
    int s0 = lane, s1 = lane + 64;
    int d0 = ((((s0 >> 3) ^ (k & 15)) << 3) | (s0 & 7));
    int d1 = ((((s1 >> 3) ^ (k & 15)) << 3) | (s1 & 7));
    shpn[(size_t)ck * NS + d0] = f2bf(v0 * rn);
    shpn[(size_t)ck * NS + d1] = f2bf(v1 * rn);
}

// K2: main kernel. Block = (wtile, kquarter, b). ALL 4 channels' B (64 KB)
// staged to LDS ONCE at block start (in flight over prologue). Compute phase:
// zero barriers, zero global ops. Wave wv: windows (wv>>1)*64..+63,
// k-half (wv&1)*32..+31 of this block's 64-k quarter.
__global__ __launch_bounds__(256, 2)
void mcs_main_kernel(const float* __restrict__ x,
                     const short* __restrict__ shpn,
                     float* __restrict__ out) {
    __shared__ bf16x8 bs[NC][KPB * 16];           // 64 KB swizzled B, all ch
    __shared__ alignas(16) short xcp[NC][4][264]; // 8.25 KB shifted raw-bf16 x
    __shared__ alignas(16) float scratch[NC][264];// x^2 -> prefix -> epilogue red
    __shared__ float invw[NC][WPB];               // 2 KB window inv-norms

    const int wt = blockIdx.x, kq = blockIdx.y, b = blockIdx.z;
    const int w0 = wt * WPB;
    const int tid = threadIdx.x;
    const int lane = tid & 63, wv = tid >> 6;

    // ---- B staging: ALL channels, once. 16 x 1KB gload_lds per wave,
    // zero VGPR / zero VALU, in flight over the entire prologue. ----
    {
        const char* gbase = (const char*)shpn + (size_t)(kq * KPB) * NS * 2;
        #pragma unroll
        for (int c = 0; c < NC; c++) {
            const char* gc = gbase + (size_t)c * NK * NS * 2;
            char* lc = (char*)&bs[c][0];
            #pragma unroll
            for (int i = 0; i < 4; i++) {
                int off = (wv * 4 + i) * 1024;
                gload_lds16(gc + off + lane * 16, lc + off);
            }
        }
    }

    // ---- stage x: thread tid holds element o=tid of each channel ----
    float xv[NC];
    #pragma unroll
    for (int c = 0; c < NC; c++) {
        int g = w0 + tid;
        xv[c] = (g < NL) ? x[((size_t)b * NC + c) * NL + g] : 0.f;
    }
    #pragma unroll
    for (int c = 0; c < NC; c++) {
        short hv = f2bf(xv[c]);                  // RAW bf16, no scaling
        #pragma unroll
        for (int r = 0; r < 4; r++) {
            int o2 = tid - r;
            if (o2 >= 0) xcp[c][r][o2] = hv;
        }
        scratch[c][tid] = xv[c] * xv[c];
    }
    __syncthreads();

    // ---- in-place inclusive prefix scan: wave wv scans channel wv ----
    {
        float4 v = *(const float4*)&scratch[wv][lane * 4];
        v.y += v.x; v.z += v.y; v.w += v.z;
        float tt = v.w;
        #pragma unroll
        for (int o = 1; o < 64; o <<= 1) {
            float u = __shfl_up(tt, o, 64);
            if (lane >= o) tt += u;
        }
        float excl = tt - v.w;
        v.x += excl; v.y += excl; v.z += excl; v.w += excl;
        *(float4*)&scratch[wv][lane * 4] = v;
    }
    __syncthreads();

    // ---- window inverse norms from prefix sums (2 per thread) ----
    #pragma unroll
    for (int i = 0; i < 2; i++) {
        int idx = tid + 256 * i;
        int c = idx >> 7, o = idx & 127;
        float nn = scratch[c][o + 127] - (o ? scratch[c][o - 1] : 0.f);
        int w = w0 + o;
        invw[c][o] = (w < NW) ? 1.f / fmaxf(sqrtf(fmaxf(nn, 0.f)), EPSF) : 0.f;
    }
    __syncthreads();   // invw visible; B staged (barrier drains vmcnt)

    // ---- compute: no barriers, no global ops until epilogue ----
    const int m = lane & 15, q = lane >> 4, r = m & 3;
    const int kh = wv & 1, wh = wv >> 1;

    floatx4 tot[4][2];
    #pragma unroll
    for (int mt = 0; mt < 4; mt++)
        #pragma unroll
        for (int kt = 0; kt < 2; kt++) tot[mt][kt] = (floatx4){0.f, 0.f, 0.f, 0.f};

    #pragma unroll
    for (int c = 0; c < NC; c++) {
        floatx4 part[4][2];
        #pragma unroll
        for (int s0 = 0; s0 < NS; s0 += 32) {
            bf16x8 a[4];
            #pragma unroll
            for (int mt = 0; mt < 4; mt++) {     // raw bit-copy: zero VALU
                int ts = wh * 64 + mt * 16 + m + s0 + q * 8;
                const uint2* pp = (const uint2*)&xcp[c][r][ts - r];
                union { uint2 uu[2]; bf16x8 v; } cv;
                cv.uu[0] = pp[0]; cv.uu[1] = pp[1];
                a[mt] = cv.v;
            }
            int cc = (s0 >> 3) + q;
            #pragma unroll
            for (int kt = 0; kt < 2; kt++) {
                int k = kh * 32 + kt * 16 + m;   // k&15 == m
                bf16x8 bf = bs[c][(k << 4) | (cc ^ m)];
                #pragma unroll
                for (int mt = 0; mt < 4; mt++) {
                    part[mt][kt] = (s0 == 0)
                        ? __builtin_amdgcn_mfma_f32_16x16x32_bf16(
                              a[mt], bf, (floatx4){0.f, 0.f, 0.f, 0.f}, 0, 0, 0)
                        : __builtin_amdgcn_mfma_f32_16x16x32_bf16(
                              a[mt], bf, part[mt][kt], 0, 0, 0);
                }
            }
        }
        // fp32 per-channel scale-accumulate: tot += invw[row] * part
        #pragma unroll
        for (int mt = 0; mt < 4; mt++) {
            const float4 iv = *(const float4*)&invw[c][wh * 64 + mt * 16 + q * 4];
            floatx4 ivv = (floatx4){iv.x, iv.y, iv.z, iv.w};
            #pragma unroll
            for (int kt = 0; kt < 2; kt++) tot[mt][kt] += ivv * part[mt][kt];
        }
    }

    // ---- epilogue: max over wave's 64 windows per k, then atomicMax.
    // scratch[wv] written only by wave wv (all prologue reads are behind the
    // pre-compute barrier), so no barrier needed before these writes. ----
    #pragma unroll
    for (int kt = 0; kt < 2; kt++) {
        floatx4 v0 = tot[0][kt], v1 = tot[1][kt], v2 = tot[2][kt], v3 = tot[3][kt];
        float mx = fmaxf(fmaxf(fmaxf(v0.x, v0.y), fmaxf(v0.z, v0.w)),
                         fmaxf(fmaxf(v1.x, v1.y), fmaxf(v1.z, v1.w)));
        mx = fmaxf(mx, fmaxf(fmaxf(fmaxf(v2.x, v2.y), fmaxf(v2.z, v2.w)),
                             fmaxf(fmaxf(v3.x, v3.y), fmaxf(v3.z, v3.w))));
        mx = fmaxf(mx, __shfl_xor(mx, 16, 64));
        mx = fmaxf(mx, __shfl_xor(mx, 32, 64));
        if (lane < 16) scratch[wv][kt * 16 + lane] = mx;   // own row, no race
    }
    __syncthreads();
    if (tid < 64) {
        int khh = tid >> 5, j = tid & 31;
        // k-half khh computed by waves {khh, khh+2} (two window halves)
        float v = fmaxf(scratch[khh][j], scratch[khh + 2][j]);
        v = fmaxf(v, 0.f) * 0.25f;    // ReLU + 1/C, nonneg -> int-monotonic
        int kg = kq * KPB + khh * 32 + j;
        atomicMax((int*)out + (size_t)b * NK + kg, __float_as_int(v));
    }
}

extern "C" void kernel_launch(void* const* d_in, const int* in_sizes, int n_in,
                              void* d_out, int out_size, void* d_ws, size_t ws_size,
                              hipStream_t stream) {
    (void)in_sizes; (void)n_in; (void)out_size; (void)ws_size;
    const float* x   = (const float*)d_in[0];
    const float* shp = (const float*)d_in[1];
    float* out = (float*)d_out;

    short* shpn = (short*)d_ws;     // 256 KB of workspace

    norm_shp_kernel<<<NC * NK, 64, 0, stream>>>(shp, shpn);
    mcs_main_kernel<<<dim3(NWT, 4, NB), 256, 0, stream>>>(x, shpn, out);
}

// Round 4
// 76.558 us; speedup vs baseline: 1.9146x; 1.0548x over previous
//
#include <hip/hip_runtime.h>
#include <hip/hip_bf16.h>

#define NB 16
#define NC 4
#define NL 4096
#define NK 256
#define NS 128
#define NW (NL - NS + 1)           /* 3969 */
#define WPB 128                    /* windows per block */
#define NWT ((NW + WPB - 1) / WPB) /* 32 window tiles */
#define KPB 64                     /* k per block (K split 4-way) */
#define EPSF 1e-8f

typedef __attribute__((ext_vector_type(8))) short bf16x8;
typedef __attribute__((ext_vector_type(4))) float floatx4;

typedef __attribute__((address_space(3))) unsigned int* lds_ptr_t;
typedef const __attribute__((address_space(1))) unsigned int* gbl_ptr_t;

__device__ inline short f2bf(float f) {
    __hip_bfloat16 h = __float2bfloat16(f);
    short s;
    __builtin_memcpy(&s, &h, sizeof(short));
    return s;
}

__device__ inline void gload_lds16(const void* g, void* l) {
    __builtin_amdgcn_global_load_lds((gbl_ptr_t)g, (lds_ptr_t)l, 16, 0, 0);
}

// K1: normalize shapelets (fp32 in), write bf16 bits PRE-SWIZZLED within each
// 256B row so the main kernel can global_load_lds linearly. One wave per (c,k).
__global__ __launch_bounds__(64)
void norm_shp_kernel(const float* __restrict__ shp, short* __restrict__ shpn) {
    int ck = blockIdx.x;
    int k = ck & (NK - 1);
    int lane = threadIdx.x;
    const float* p = shp + (size_t)ck * NS;
    float v0 = p[lane];
    float v1 = p[lane + 64];
    float ss = v0 * v0 + v1 * v1;
    #pragma unroll
    for (int o = 32; o > 0; o >>= 1) ss += __shfl_xor(ss, o, 64);
    float rn = 1.f / fmaxf(sqrtf(ss), EPSF);
    // swizzled element positions: 16B unit u of row k goes to unit u^(k&15)
    int s0 = lane, s1 = lane + 64;
    int d0 = ((((s0 >> 3) ^ (k & 15)) << 3) | (s0 & 7));
    int d1 = ((((s1 >> 3) ^ (k & 15)) << 3) | (s1 & 7));
    shpn[(size_t)ck * NS + d0] = f2bf(v0 * rn);
    shpn[(size_t)ck * NS + d1] = f2bf(v1 * rn);
}

// K2: task-looped main kernel. Grid = (kq=4, slot=128) = 512 blocks = 2/CU.
// Each block stages all 4 channels' B for its 64-k quarter ONCE (64 KB), then
// loops over 4 (wt,b) tasks reusing it. Next task's x prefetched into regs
// over the MFMA phase. Wave wv: windows (wv>>1)*64..+63, k-half (wv&1)*32..+31.
__global__ __launch_bounds__(256, 2)
void mcs_main_kernel(const float* __restrict__ x,
                     const short* __restrict__ shpn,
                     float* __restrict__ out) {
    __shared__ bf16x8 bs[NC][KPB * 16];           // 64 KB swizzled B, all ch
    __shared__ alignas(16) short xcp[NC][4][264]; // 8.25 KB shifted raw-bf16 x
    __shared__ alignas(16) float scratch[NC][264];// x^2 -> prefix -> epilogue red
    __shared__ float invw[NC][WPB];               // 2 KB window inv-norms

    const int kq = blockIdx.x, slot = blockIdx.y;
    const int tid = threadIdx.x;
    const int lane = tid & 63, wv = tid >> 6;
    const int m = lane & 15, q = lane >> 4, r = m & 3;
    const int kh = wv & 1, wh = wv >> 1;

    // ---- B staging: ALL channels, ONCE per block. 16 x 1KB gload_lds per
    // wave, zero VGPR / zero VALU, in flight over the first task prologue. ----
    {
        const char* gbase = (const char*)shpn + (size_t)(kq * KPB) * NS * 2;
        #pragma unroll
        for (int c = 0; c < NC; c++) {
            const char* gc = gbase + (size_t)c * NK * NS * 2;
            char* lc = (char*)&bs[c][0];
            #pragma unroll
            for (int i = 0; i < 4; i++) {
                int off = (wv * 4 + i) * 1024;
                gload_lds16(gc + off + lane * 16, lc + off);
            }
        }
    }

    // ---- first task's x load (tasks: same b, 4 consecutive wt) ----
    float xv[NC];
    {
        int idx = slot * 4;
        int wt = idx & 31, b = idx >> 5;
        int g = wt * WPB + tid;
        #pragma unroll
        for (int c = 0; c < NC; c++)
            xv[c] = (g < NL) ? x[((size_t)b * NC + c) * NL + g] : 0.f;
    }

    for (int t = 0; t < 4; t++) {
        const int idx = slot * 4 + t;
        const int wt = idx & 31, b = idx >> 5;
        const int w0 = wt * WPB;

        // ---- write shift-copies (raw bf16) + squares ----
        #pragma unroll
        for (int c = 0; c < NC; c++) {
            short hv = f2bf(xv[c]);
            #pragma unroll
            for (int rr = 0; rr < 4; rr++) {
                int o2 = tid - rr;
                if (o2 >= 0) xcp[c][rr][o2] = hv;
            }
            scratch[c][tid] = xv[c] * xv[c];
        }
        __syncthreads();

        // ---- in-place inclusive prefix scan: wave wv scans channel wv ----
        {
            float4 v = *(const float4*)&scratch[wv][lane * 4];
            v.y += v.x; v.z += v.y; v.w += v.z;
            float tt = v.w;
            #pragma unroll
            for (int o = 1; o < 64; o <<= 1) {
                float u = __shfl_up(tt, o, 64);
                if (lane >= o) tt += u;
            }
            float excl = tt - v.w;
            v.x += excl; v.y += excl; v.z += excl; v.w += excl;
            *(float4*)&scratch[wv][lane * 4] = v;
        }
        __syncthreads();

        // ---- window inverse norms from prefix sums (2 per thread) ----
        #pragma unroll
        for (int i = 0; i < 2; i++) {
            int ii = tid + 256 * i;
            int c = ii >> 7, o = ii & 127;
            float nn = scratch[c][o + 127] - (o ? scratch[c][o - 1] : 0.f);
            int w = w0 + o;
            invw[c][o] = (w < NW) ? 1.f / fmaxf(sqrtf(fmaxf(nn, 0.f)), EPSF)
                                  : 0.f;
        }
        if (t == 0) asm volatile("s_waitcnt vmcnt(0)" ::: "memory"); // B staged
        __syncthreads();

        // ---- prefetch next task's x into regs (in flight over MFMA) ----
        if (t < 3) {
            int idxn = idx + 1;
            int wtn = idxn & 31, bn = idxn >> 5;
            int g = wtn * WPB + tid;
            #pragma unroll
            for (int c = 0; c < NC; c++)
                xv[c] = (g < NL) ? x[((size_t)bn * NC + c) * NL + g] : 0.f;
        }

        // ---- compute: no barriers, no waits except LDS ----
        floatx4 tot[4][2];
        #pragma unroll
        for (int mt = 0; mt < 4; mt++)
            #pragma unroll
            for (int kt = 0; kt < 2; kt++)
                tot[mt][kt] = (floatx4){0.f, 0.f, 0.f, 0.f};

        #pragma unroll
        for (int c = 0; c < NC; c++) {
            floatx4 part[4][2];
            #pragma unroll
            for (int s0 = 0; s0 < NS; s0 += 32) {
                bf16x8 a[4];
                #pragma unroll
                for (int mt = 0; mt < 4; mt++) {   // raw bit-copy: zero VALU
                    int ts = wh * 64 + mt * 16 + m + s0 + q * 8;
                    const uint2* pp = (const uint2*)&xcp[c][r][ts - r];
                    union { uint2 uu[2]; bf16x8 v; } cv;
                    cv.uu[0] = pp[0]; cv.uu[1] = pp[1];
                    a[mt] = cv.v;
                }
                int cc = (s0 >> 3) + q;
                #pragma unroll
                for (int kt = 0; kt < 2; kt++) {
                    int k = kh * 32 + kt * 16 + m;   // k&15 == m
                    bf16x8 bf = bs[c][(k << 4) | (cc ^ m)];
                    #pragma unroll
                    for (int mt = 0; mt < 4; mt++) {
                        part[mt][kt] = (s0 == 0)
                            ? __builtin_amdgcn_mfma_f32_16x16x32_bf16(
                                  a[mt], bf, (floatx4){0.f,0.f,0.f,0.f}, 0,0,0)
                            : __builtin_amdgcn_mfma_f32_16x16x32_bf16(
                                  a[mt], bf, part[mt][kt], 0, 0, 0);
                    }
                }
            }
            // fp32 per-channel scale-accumulate: tot += invw[row] * part
            #pragma unroll
            for (int mt = 0; mt < 4; mt++) {
                const float4 iv =
                    *(const float4*)&invw[c][wh * 64 + mt * 16 + q * 4];
                floatx4 ivv = (floatx4){iv.x, iv.y, iv.z, iv.w};
                #pragma unroll
                for (int kt = 0; kt < 2; kt++) tot[mt][kt] += ivv * part[mt][kt];
            }
        }

        // ---- epilogue: wave-max per k, then atomicMax. scratch rows are
        // per-wave (all cross-wave scratch reads are behind barriers). ----
        #pragma unroll
        for (int kt = 0; kt < 2; kt++) {
            floatx4 v0 = tot[0][kt], v1 = tot[1][kt],
                    v2 = tot[2][kt], v3 = tot[3][kt];
            float mx = fmaxf(fmaxf(fmaxf(v0.x, v0.y), fmaxf(v0.z, v0.w)),
                             fmaxf(fmaxf(v1.x, v1.y), fmaxf(v1.z, v1.w)));
            mx = fmaxf(mx, fmaxf(fmaxf(fmaxf(v2.x, v2.y), fmaxf(v2.z, v2.w)),
                                 fmaxf(fmaxf(v3.x, v3.y), fmaxf(v3.z, v3.w))));
            mx = fmaxf(mx, __shfl_xor(mx, 16, 64));
            mx = fmaxf(mx, __shfl_xor(mx, 32, 64));
            if (lane < 16) scratch[wv][kt * 16 + lane] = mx;
        }
        __syncthreads();
        if (tid < 64) {
            int khh = tid >> 5, j = tid & 31;
            // k-half khh computed by waves {khh, khh+2} (two window halves)
            float v = fmaxf(scratch[khh][j], scratch[khh + 2][j]);
            v = fmaxf(v, 0.f) * 0.25f;   // ReLU + 1/C, nonneg -> int-monotonic
            int kg = kq * KPB + khh * 32 + j;
            atomicMax((int*)out + (size_t)b * NK + kg, __float_as_int(v));
        }
        __syncthreads();   // reduce done reading scratch before next task
    }
}

extern "C" void kernel_launch(void* const* d_in, const int* in_sizes, int n_in,
                              void* d_out, int out_size, void* d_ws, size_t ws_size,
                              hipStream_t stream) {
    (void)in_sizes; (void)n_in; (void)out_size; (void)ws_size;
    const float* x   = (const float*)d_in[0];
    const float* shp = (const float*)d_in[1];
    float* out = (float*)d_out;

    short* shpn = (short*)d_ws;     // 256 KB of workspace

    norm_shp_kernel<<<NC * NK, 64, 0, stream>>>(shp, shpn);
    mcs_main_kernel<<<dim3(4, 128), 256, 0, stream>>>(x, shpn, out);
}

// Round 5
// 75.942 us; speedup vs baseline: 1.9302x; 1.0081x over previous
//
#include <hip/hip_runtime.h>
#include <hip/hip_bf16.h>

#define NB 16
#define NC 4
#define NL 4096
#define NK 256
#define NS 128
#define NW (NL - NS + 1)           /* 3969 */
#define WPB 128                    /* windows per block */
#define NWT ((NW + WPB - 1) / WPB) /* 32 window tiles */
#define KPB 64                     /* k per block (K split 4-way) */
#define EPSF 1e-8f

typedef __attribute__((ext_vector_type(8))) short bf16x8;
typedef __attribute__((ext_vector_type(4))) float floatx4;

typedef __attribute__((address_space(3))) unsigned int* lds_ptr_t;
typedef const __attribute__((address_space(1))) unsigned int* gbl_ptr_t;

__device__ inline short f2bf(float f) {
    __hip_bfloat16 h = __float2bfloat16(f);
    short s;
    __builtin_memcpy(&s, &h, sizeof(short));
    return s;
}

__device__ inline void gload_lds16(const void* g, void* l) {
    __builtin_amdgcn_global_load_lds((gbl_ptr_t)g, (lds_ptr_t)l, 16, 0, 0);
}

// K1: normalize shapelets (fp32 in), write bf16 bits PRE-SWIZZLED within each
// 256B row so the main kernel can global_load_lds linearly. One wave per (c,k).
__global__ __launch_bounds__(64)
void norm_shp_kernel(const float* __restrict__ shp, short* __restrict__ shpn) {
    int ck = blockIdx.x;
    int k = ck & (NK - 1);
    int lane = threadIdx.x;
    const float* p = shp + (size_t)ck * NS;
    float v0 = p[lane];
    float v1 = p[lane + 64];
    float ss = v0 * v0 + v1 * v1;
    #pragma unroll
    for (int o = 32; o > 0; o >>= 1) ss += __shfl_xor(ss, o, 64);
    float rn = 1.f / fmaxf(sqrtf(ss), EPSF);
    // swizzled element positions: 16B unit u of row k goes to unit u^(k&15)
    int s0 = lane, s1 = lane + 64;
    int d0 = ((((s0 >> 3) ^ (k & 15)) << 3) | (s0 & 7));
    int d1 = ((((s1 >> 3) ^ (k & 15)) << 3) | (s1 & 7));
    shpn[(size_t)ck * NS + d0] = f2bf(v0 * rn);
    shpn[(size_t)ck * NS + d1] = f2bf(v1 * rn);
}

// K2: task-looped main kernel. Grid = (kq=4, slot=128) = 512 blocks = 2/CU.
// ALL global reads (B for the k-quarter + all 4 tasks' x) issued in ONE burst
// at block entry; the 4 tasks then run with zero global reads. atomicMax
// deferred to kernel end so per-task barriers never drain atomic traffic.
__global__ __launch_bounds__(256, 2)
void mcs_main_kernel(const float* __restrict__ x,
                     const short* __restrict__ shpn,
                     float* __restrict__ out) {
    __shared__ bf16x8 bs[NC][KPB * 16];           // 64 KB swizzled B, all ch
    __shared__ alignas(16) short xcp[NC][4][264]; // 8.25 KB shifted raw-bf16 x
    __shared__ alignas(16) float scratch[NC][264];// x^2 -> prefix -> epilogue red
    __shared__ float invw[NC][WPB];               // 2 KB window inv-norms

    const int kq = blockIdx.x, slot = blockIdx.y;
    const int tid = threadIdx.x;
    const int lane = tid & 63, wv = tid >> 6;
    const int m = lane & 15, q = lane >> 4, r = m & 3;
    const int kh = wv & 1, wh = wv >> 1;

    // ---- ONE memory burst: all 4 tasks' x (16 loads) ... ----
    float xv[16];
    #pragma unroll
    for (int t = 0; t < 4; t++) {
        const int idx = slot * 4 + t;
        const int wt = idx & 31, b = idx >> 5;
        const int g = wt * WPB + tid;
        #pragma unroll
        for (int c = 0; c < NC; c++)
            xv[t * 4 + c] = (g < NL) ? x[((size_t)b * NC + c) * NL + g] : 0.f;
    }
    // ---- ... plus all of B via gload_lds (16 x 1KB/wave, zero VGPR) ----
    {
        const char* gbase = (const char*)shpn + (size_t)(kq * KPB) * NS * 2;
        #pragma unroll
        for (int c = 0; c < NC; c++) {
            const char* gc = gbase + (size_t)c * NK * NS * 2;
            char* lc = (char*)&bs[c][0];
            #pragma unroll
            for (int i = 0; i < 4; i++) {
                int off = (wv * 4 + i) * 1024;
                gload_lds16(gc + off + lane * 16, lc + off);
            }
        }
    }

    float res[4];

    #pragma unroll
    for (int t = 0; t < 4; t++) {
        const int idx = slot * 4 + t;
        const int wt = idx & 31;
        const int w0 = wt * WPB;

        // ---- write shift-copies (raw bf16) + squares, from registers ----
        #pragma unroll
        for (int c = 0; c < NC; c++) {
            float xf = xv[t * 4 + c];
            short hv = f2bf(xf);
            #pragma unroll
            for (int rr = 0; rr < 4; rr++) {
                int o2 = tid - rr;
                if (o2 >= 0) xcp[c][rr][o2] = hv;
            }
            scratch[c][tid] = xf * xf;
        }
        __syncthreads();

        // ---- in-place inclusive prefix scan: wave wv scans channel wv ----
        {
            float4 v = *(const float4*)&scratch[wv][lane * 4];
            v.y += v.x; v.z += v.y; v.w += v.z;
            float tt = v.w;
            #pragma unroll
            for (int o = 1; o < 64; o <<= 1) {
                float u = __shfl_up(tt, o, 64);
                if (lane >= o) tt += u;
            }
            float excl = tt - v.w;
            v.x += excl; v.y += excl; v.z += excl; v.w += excl;
            *(float4*)&scratch[wv][lane * 4] = v;
        }
        __syncthreads();

        // ---- window inverse norms from prefix sums (2 per thread) ----
        #pragma unroll
        for (int i = 0; i < 2; i++) {
            int ii = tid + 256 * i;
            int c = ii >> 7, o = ii & 127;
            float nn = scratch[c][o + 127] - (o ? scratch[c][o - 1] : 0.f);
            int w = w0 + o;
            invw[c][o] = (w < NW) ? 1.f / fmaxf(sqrtf(fmaxf(nn, 0.f)), EPSF)
                                  : 0.f;
        }
        if (t == 0) asm volatile("s_waitcnt vmcnt(0)" ::: "memory"); // burst done
        __syncthreads();

        // ---- compute: zero global ops, zero waits except LDS ----
        floatx4 tot[4][2];
        #pragma unroll
        for (int mt = 0; mt < 4; mt++)
            #pragma unroll
            for (int kt = 0; kt < 2; kt++)
                tot[mt][kt] = (floatx4){0.f, 0.f, 0.f, 0.f};

        #pragma unroll
        for (int c = 0; c < NC; c++) {
            floatx4 part[4][2];
            #pragma unroll
            for (int s0 = 0; s0 < NS; s0 += 32) {
                bf16x8 a[4];
                #pragma unroll
                for (int mt = 0; mt < 4; mt++) {   // raw bit-copy: zero VALU
                    int ts = wh * 64 + mt * 16 + m + s0 + q * 8;
                    const uint2* pp = (const uint2*)&xcp[c][r][ts - r];
                    union { uint2 uu[2]; bf16x8 v; } cv;
                    cv.uu[0] = pp[0]; cv.uu[1] = pp[1];
                    a[mt] = cv.v;
                }
                int cc = (s0 >> 3) + q;
                #pragma unroll
                for (int kt = 0; kt < 2; kt++) {
                    int k = kh * 32 + kt * 16 + m;   // k&15 == m
                    bf16x8 bf = bs[c][(k << 4) | (cc ^ m)];
                    #pragma unroll
                    for (int mt = 0; mt < 4; mt++) {
                        part[mt][kt] = (s0 == 0)
                            ? __builtin_amdgcn_mfma_f32_16x16x32_bf16(
                                  a[mt], bf, (floatx4){0.f,0.f,0.f,0.f}, 0,0,0)
                            : __builtin_amdgcn_mfma_f32_16x16x32_bf16(
                                  a[mt], bf, part[mt][kt], 0, 0, 0);
                    }
                }
            }
            // fp32 per-channel scale-accumulate: tot += invw[row] * part
            #pragma unroll
            for (int mt = 0; mt < 4; mt++) {
                const float4 iv =
                    *(const float4*)&invw[c][wh * 64 + mt * 16 + q * 4];
                floatx4 ivv = (floatx4){iv.x, iv.y, iv.z, iv.w};
                #pragma unroll
                for (int kt = 0; kt < 2; kt++) tot[mt][kt] += ivv * part[mt][kt];
            }
        }

        // ---- epilogue: wave-max per k into scratch, reduce into res[t] ----
        #pragma unroll
        for (int kt = 0; kt < 2; kt++) {
            floatx4 v0 = tot[0][kt], v1 = tot[1][kt],
                    v2 = tot[2][kt], v3 = tot[3][kt];
            float mx = fmaxf(fmaxf(fmaxf(v0.x, v0.y), fmaxf(v0.z, v0.w)),
                             fmaxf(fmaxf(v1.x, v1.y), fmaxf(v1.z, v1.w)));
            mx = fmaxf(mx, fmaxf(fmaxf(fmaxf(v2.x, v2.y), fmaxf(v2.z, v2.w)),
                                 fmaxf(fmaxf(v3.x, v3.y), fmaxf(v3.z, v3.w))));
            mx = fmaxf(mx, __shfl_xor(mx, 16, 64));
            mx = fmaxf(mx, __shfl_xor(mx, 32, 64));
            if (lane < 16) scratch[wv][kt * 16 + lane] = mx;
        }
        __syncthreads();
        if (tid < 64) {
            int khh = tid >> 5, j = tid & 31;
            // k-half khh computed by waves {khh, khh+2} (two window halves)
            float v = fmaxf(scratch[khh][j], scratch[khh + 2][j]);
            res[t] = fmaxf(v, 0.f) * 0.25f;   // ReLU + 1/C
        }
        __syncthreads();   // reduce done reading scratch before next task
    }

    // ---- deferred atomics: fire-and-forget, no barrier follows ----
    if (tid < 64) {
        int khh = tid >> 5, j = tid & 31;
        int kg = kq * KPB + khh * 32 + j;
        #pragma unroll
        for (int t = 0; t < 4; t++) {
            int b = (slot * 4 + t) >> 5;
            atomicMax((int*)out + (size_t)b * NK + kg, __float_as_int(res[t]));
        }
    }
}

extern "C" void kernel_launch(void* const* d_in, const int* in_sizes, int n_in,
                              void* d_out, int out_size, void* d_ws, size_t ws_size,
                              hipStream_t stream) {
    (void)in_sizes; (void)n_in; (void)out_size; (void)ws_size;
    const float* x   = (const float*)d_in[0];
    const float* shp = (const float*)d_in[1];
    float* out = (float*)d_out;

    short* shpn = (short*)d_ws;     // 256 KB of workspace

    norm_shp_kernel<<<NC * NK, 64, 0, stream>>>(shp, shpn);
    mcs_main_kernel<<<dim3(4, 128), 256, 0, stream>>>(x, shpn, out);
}